// Round 6
// baseline (69.515 us; speedup 1.0000x reference)
//
#include <hip/hip_runtime.h>
#include <math.h>

#define BLOCK 256
#define SPLIT 4            // threads cooperating per pixel-pair
#define PPT   2            // pixels per thread
#define MAX_KV_LDS 1024    // vertex cap for LDS staging (+1 duplicate slot)

__device__ __forceinline__ float rcp1(float x)  { return __builtin_amdgcn_rcpf(x); }
__device__ __forceinline__ float rsq1(float x)  { return __builtin_amdgcn_rsqf(x); }
__device__ __forceinline__ float sqrt1(float x) { return __builtin_amdgcn_sqrtf(x); }

// term = tanh(1e5*cross) * acos(clamp(dot * rsqrt(cross^2 + dot^2)))
// (cross^2 + dot^2 == |diff|^2 |roll|^2 exactly, so no separate norms)
__device__ __forceinline__ float edge_term_s(float cr, float dt)
{
    float n2 = fmaf(cr, cr, dt * dt);
    float co = dt * rsq1(n2);
    co = __builtin_amdgcn_fmed3f(co, -0.99999f, 0.99999f);
    float y = fabsf(co);
    float p = fmaf(fmaf(fmaf(-0.0187293f, y, 0.0742610f), y, -0.2121144f),
                   y, 1.5707288f);                       // A&S 4.4.45
    float a = sqrt1(1.0f - y) * p;
    a = (co >= 0.0f) ? a : (3.14159265358979f - a);
    // tanh(1e5*cr) via Pade(5,4), clamped
    float t  = cr * 100000.0f;
    float s  = t * t;
    float nm = t * fmaf(s + 105.0f, s, 945.0f);
    float qd = fmaf(fmaf(15.0f, s, 420.0f), s, 945.0f);
    float th = __builtin_amdgcn_fmed3f(nm * rcp1(qd), -1.0f, 1.0f);
    return th * a;
}

__global__ __launch_bounds__(BLOCK, 8)
void contour_mask_kernel(const float2* __restrict__ contour,
                         const int* __restrict__ size_ptr,
                         float* __restrict__ out,
                         int out_size, int in0_elems)
{
    __shared__ float2 verts[MAX_KV_LDS + 1];

    const int size     = *size_ptr;            // wave-uniform scalar load
    const int S2       = size * size;
    const int bn_total = out_size / S2;
    const int kv       = in0_elems / (bn_total * 2);

    const int tid  = threadIdx.x;
    const int PIX_PER_BLOCK = (BLOCK / SPLIT) * PPT;     // 128
    const int base = blockIdx.x * PIX_PER_BLOCK;

    const int bn0 = base / S2;                 // uniform (scalar) divide
    const int rem = base - bn0 * S2;
    const bool one_image = (rem + PIX_PER_BLOCK <= S2) &&
                           (base + PIX_PER_BLOCK <= out_size);
    const bool use_lds = (kv <= MAX_KV_LDS) && one_image;

    if (use_lds) {
        for (int i = tid; i < kv; i += BLOCK)
            verts[i] = contour[(size_t)bn0 * kv + i];
        if (tid == 0)
            verts[kv] = contour[(size_t)bn0 * kv];   // wraparound duplicate
    }
    __syncthreads();

    const int seg = tid & (SPLIT - 1);
    const float inv_size = 1.0f / (float)size;
    const float INV2PI = 0.15915494309189535f;

    // HOT: kv==64 (16 edges/seg, fully unrolled), even size, one image in LDS
    if (use_lds && kv == 64 && (size & 1) == 0) {
        const int pi0 = rem / size;            // uniform
        const int pj0 = rem - pi0 * size;      // even (base mult of 128, size even)
        const int t   = (tid / SPLIT) * PPT;   // even local pixel offset

        int pjA = pj0 + t, piA = pi0;
        while (pjA >= size) { pjA -= size; ++piA; }   // pjA stays even
        // pair shares the row: piB==piA, pjB==pjA+1 (<size since pjA even)

        const float mx  = (float)piA * inv_size;      // mesh ch0 = i/size
        const float myA = (float)pjA * inv_size;      // mesh ch1 = j/size

        const int k0 = seg * 16;
        float2 v = verts[k0];
        float dx  = v.x - mx;
        float dyA = v.y - myA;
        float dyB = dyA - inv_size;            // v.y - myB
        float accA = 0.0f, accB = 0.0f;

        #pragma unroll
        for (int k = 0; k < 16; ++k) {
            float2 vn = verts[k0 + k + 1];     // imm-offset ds_read_b64
            float rx  = vn.x - mx;             // shared by both pixels
            float ryA = vn.y - myA;
            float ryB = ryA - inv_size;
            float P   = dx * rx;               // shared dot partial
            float dtA = fmaf(dyA, ryA, P);
            float dtB = fmaf(dyB, ryB, P);
            float crA = fmaf(dyA, rx, -(dx * ryA));   // diff.y*roll.x - diff.x*roll.y
            float crB = fmaf(dyB, rx, -(dx * ryB));
            accA += edge_term_s(crA, dtA);
            accB += edge_term_s(crB, dtB);
            dx = rx; dyA = ryA; dyB = ryB;
        }

        accA += __shfl_xor(accA, 1, 64);
        accB += __shfl_xor(accB, 1, 64);
        accA += __shfl_xor(accA, 2, 64);
        accB += __shfl_xor(accB, 2, 64);

        if (seg == 0) {
            float2 res;
            res.x = fminf(fabsf(accA) * INV2PI, 1.0f);
            res.y = fminf(fabsf(accB) * INV2PI, 1.0f);
            *(float2*)(out + base + t) = res;  // coalesced 8B store
        }
        return;
    }

    // COLD fallback: generic sizes/kv, global-memory vertex reads
    const int q  = (kv + SPLIT - 1) / SPLIT;
    const int k0 = min(seg * q, kv);
    const int k1 = min(k0 + q, kv);

    #pragma unroll
    for (int px = 0; px < PPT; ++px) {
        const int pixel = base + (tid / SPLIT) * PPT + px;
        float a = 0.0f;
        if (pixel < out_size && k0 < k1) {
            const int bn = pixel / S2;
            const int p  = pixel - bn * S2;
            const int pi = p / size;
            const int pj = p - pi * size;
            const float mxs = pi * inv_size;
            const float mys = pj * inv_size;
            const float2* vsrc = contour + (size_t)bn * kv;
            float2 v = vsrc[k0];
            float dx = v.x - mxs, dy = v.y - mys;
            for (int k = k0; k < k1; ++k) {
                int kn = k + 1; if (kn == kv) kn = 0;
                float2 vn = vsrc[kn];
                float rx = vn.x - mxs, ry = vn.y - mys;
                float cr = fmaf(dy, rx, -(dx * ry));
                float dt = fmaf(dx, rx, dy * ry);
                a += edge_term_s(cr, dt);
                dx = rx; dy = ry;
            }
        }
        a += __shfl_xor(a, 1, 64);
        a += __shfl_xor(a, 2, 64);
        if (pixel < out_size && seg == 0)
            out[pixel] = fminf(fabsf(a) * INV2PI, 1.0f);
    }
}

extern "C" void kernel_launch(void* const* d_in, const int* in_sizes, int n_in,
                              void* d_out, int out_size, void* d_ws, size_t ws_size,
                              hipStream_t stream)
{
    const float2* contour  = (const float2*)d_in[0];
    const int*    size_ptr = (const int*)d_in[1];
    float*        out      = (float*)d_out;

    const int PIX_PER_BLOCK = (BLOCK / SPLIT) * PPT;   // 128 pixels per block
    const int blocks = (out_size + PIX_PER_BLOCK - 1) / PIX_PER_BLOCK;
    contour_mask_kernel<<<blocks, BLOCK, 0, stream>>>(
        contour, size_ptr, out, out_size, in_sizes[0]);
}